// Round 4
// baseline (276.032 us; speedup 1.0000x reference)
//
#include <hip/hip_runtime.h>
#include <hip/hip_cooperative_groups.h>

namespace cg = cooperative_groups;

#define NN 50000
#define DD 64
#define EE 800000
#define NB 196      // ceil(NN/256) cnt-zeroing blocks (fallback linear kernel)
#define NTILE 3125  // NN/16 row tiles (exact)
#define NSLICE 128  // edge slices for scatter
#define ESL 6250    // EE/NSLICE edges per slice
#define DRNG 6250   // NN/8 dst nodes per XCD range
#define BCAP 64     // bucket capacity per node (P(deg>64) ~ 1e-14 for Poisson(16))
#define NVB 1024    // virtual scatter blocks (NSLICE*8)
#define GRID 512    // 2 blocks/CU: conservative co-residency for coop launch

typedef unsigned short u16;
typedef unsigned int u32;
typedef __attribute__((ext_vector_type(8))) short bf16x8;
typedef __attribute__((ext_vector_type(4))) float f32x4;

__device__ __forceinline__ float bf2f(u16 u) {
  u32 t = ((u32)u) << 16;
  return __builtin_bit_cast(float, t);
}
__device__ __forceinline__ u16 f2bf(float f) {
  u32 b = __builtin_bit_cast(u32, f);
  u32 r = (b + 0x7FFF + ((b >> 16) & 1)) >> 16;
  return (u16)r;
}

// ---------------------------------------------------------------------------
// linear part: x = nf @ W.T + b_lin, bf16 out, interleaved [N][64] rows.
// C/D mapping: col=lane&15, row=(lane>>4)*4+reg  [verified m89/m91]
// ---------------------------------------------------------------------------
template <int STRIDE>
__device__ __forceinline__ void do_linear(const float* __restrict__ nf,
                                          const float* __restrict__ b_lin,
                                          u16* __restrict__ x16,
                                          const u16* Wsh, int tid) {
  int wave = tid >> 6;
  int lane = tid & 63;
  int m = lane & 15;
  int quad = lane >> 4;
#pragma unroll 1
  for (int tile = blockIdx.x * 4 + wave; tile < NTILE; tile += STRIDE * 4) {
    int rowbase = tile * 16;

    bf16x8 bfrag[4][2];
#pragma unroll
    for (int c = 0; c < 4; ++c) {
#pragma unroll
      for (int ks = 0; ks < 2; ++ks) {
        const u16* p = &Wsh[(c * 16 + m) * 72 + ks * 32 + quad * 8];
        bfrag[c][ks] = *(const bf16x8*)p;
      }
    }

    bf16x8 afrag[2];
#pragma unroll
    for (int ks = 0; ks < 2; ++ks) {
      const float* p = nf + (rowbase + m) * DD + ks * 32 + quad * 8;
      float4 lo = *(const float4*)p;
      float4 hi = *(const float4*)(p + 4);
      bf16x8 a;
      a[0] = (short)f2bf(lo.x); a[1] = (short)f2bf(lo.y);
      a[2] = (short)f2bf(lo.z); a[3] = (short)f2bf(lo.w);
      a[4] = (short)f2bf(hi.x); a[5] = (short)f2bf(hi.y);
      a[6] = (short)f2bf(hi.z); a[7] = (short)f2bf(hi.w);
      afrag[ks] = a;
    }

    f32x4 acc[4];
#pragma unroll
    for (int c = 0; c < 4; ++c) {
      acc[c][0] = 0.0f; acc[c][1] = 0.0f; acc[c][2] = 0.0f; acc[c][3] = 0.0f;
    }
#pragma unroll
    for (int c = 0; c < 4; ++c) {
      acc[c] = __builtin_amdgcn_mfma_f32_16x16x32_bf16(afrag[0], bfrag[c][0], acc[c], 0, 0, 0);
      acc[c] = __builtin_amdgcn_mfma_f32_16x16x32_bf16(afrag[1], bfrag[c][1], acc[c], 0, 0, 0);
    }

#pragma unroll
    for (int c = 0; c < 4; ++c) {
      int gcol = c * 16 + m;
      float bl = b_lin[gcol];
#pragma unroll
      for (int r = 0; r < 4; ++r) {
        int grow = rowbase + quad * 4 + r;
        x16[grow * DD + gcol] = f2bf(acc[c][r] + bl);
      }
    }
  }
}

// ---------------------------------------------------------------------------
// scatter part (bucketed): pos = atomicAdd claims a slot; cnt[] doubles as
// claim counter and final degree. XCD-sliced: virtual block vb handles dst
// range r=vb&7 over edge slice sl=vb>>3. With GRID=512 each block walks 2
// vbs that share the same r (512 % 8 == 0): one dst range per block.
// pos>=BCAP claims dropped (keeps writes in-bounds unconditionally).
// ---------------------------------------------------------------------------
template <int STRIDE>
__device__ __forceinline__ void do_scatter(const int* __restrict__ ei,
                                           int* __restrict__ cnt,
                                           u16* __restrict__ bucket, int tid) {
#pragma unroll 1
  for (int vb = blockIdx.x; vb < NVB; vb += STRIDE) {
    int r = vb & 7;
    int sl = vb >> 3;
    int rlo = r * DRNG;
    int ebase = sl * ESL;
    int eend = ebase + ESL;
#pragma unroll 1
    for (int it = 0; it < 13; ++it) {
      int e = ebase + it * 512 + tid * 2;
      if (e < eend) {
        int4 p = *(const int4*)(ei + 2 * e);  // (src0,dst0,src1,dst1)
        if ((u32)(p.y - rlo) < (u32)DRNG) {
          int pos = atomicAdd(&cnt[p.y], 1);
          if (pos < BCAP) bucket[p.y * BCAP + pos] = (u16)p.x;
        }
        if ((u32)(p.w - rlo) < (u32)DRNG) {
          int pos = atomicAdd(&cnt[p.w], 1);
          if (pos < BCAP) bucket[p.w * BCAP + pos] = (u16)p.z;
        }
      }
    }
  }
}

// ---------------------------------------------------------------------------
// gather chunk: readlane broadcasts bucket entries to SGPR so row loads
// issue off scalar bases with high MLP. Lanes >= deg hold garbage u16
// indices; reads stay inside d_ws (8.4 MB) and contributions are
// cndmask-gated to 0 (NaN-safe: select, not multiply).
// ---------------------------------------------------------------------------
template <int BASE, int LEN>
__device__ __forceinline__ float chunkN(int my, int n,
                                        const u16* __restrict__ x16, int j) {
  float v[LEN];
#pragma unroll
  for (int k = 0; k < LEN; ++k) {
    int s = __builtin_amdgcn_readlane(my, BASE + k);
    v[k] = bf2f(x16[s * DD + j]);
  }
  float a = 0.0f;
#pragma unroll
  for (int k = 0; k < LEN; ++k) a += (BASE + k < n) ? v[k] : 0.0f;
  return a;
}

__device__ __forceinline__ float gather_node(int i, int deg,
                                             const u16* __restrict__ x16,
                                             const u16* __restrict__ bucket,
                                             int j) {
  int win = deg < BCAP ? deg : BCAP;
  int my = (int)bucket[i * BCAP + j];
  float acc = chunkN<0, 16>(my, win, x16, j);
  if (win > 16) acc += chunkN<16, 8>(my, win, x16, j);
  if (win > 24) acc += chunkN<24, 8>(my, win, x16, j);
  if (win > 32) acc += chunkN<32, 8>(my, win, x16, j);
  if (win > 40) acc += chunkN<40, 8>(my, win, x16, j);
  if (win > 48) acc += chunkN<48, 8>(my, win, x16, j);
  if (win > 56) acc += chunkN<56, 8>(my, win, x16, j);
  return acc;
}

// ---------------------------------------------------------------------------
// mega (cooperative): phase0 {zero cnt, stage W} -> sync -> phase1
// {linear || scatter, parity-ordered} -> sync -> phase2 {gather}.
// One dispatch: removes 2 launch/drain gaps vs the 3-kernel pipeline.
// GRID=512 @ (256,2): 2 blocks/CU co-residency with 2x headroom.
// ---------------------------------------------------------------------------
__global__ __launch_bounds__(256, 2) void mega_kernel(
    const float* __restrict__ nf, const int* __restrict__ ei,
    const float* __restrict__ W, const float* __restrict__ b_lin,
    const float* __restrict__ bias, u16* __restrict__ x16,
    u16* __restrict__ bucket, int* __restrict__ cnt,
    float* __restrict__ out) {
  __shared__ u16 Wsh[64 * 72];
  int tid = threadIdx.x;
  cg::grid_group grid = cg::this_grid();

  // phase 0: zero claim counters + stage W to LDS.
#pragma unroll 1
  for (int i = blockIdx.x * 256 + tid; i < NN; i += GRID * 256)
    __hip_atomic_store(&cnt[i], 0, __ATOMIC_RELAXED, __HIP_MEMORY_SCOPE_AGENT);
#pragma unroll
  for (int s = 0; s < 16; ++s) {
    int idx = s * 256 + tid;
    Wsh[(idx >> 6) * 72 + (idx & 63)] = f2bf(W[idx]);
  }
  grid.sync();  // Wsh ready (block barrier) + cnt zeroed grid-wide

  // phase 1: independent halves; parity order staggers MFMA/HBM work
  // against atomic-latency work across the machine.
  if (blockIdx.x & 1) {
    do_scatter<GRID>(ei, cnt, bucket, tid);
    do_linear<GRID>(nf, b_lin, x16, Wsh, tid);
  } else {
    do_linear<GRID>(nf, b_lin, x16, Wsh, tid);
    do_scatter<GRID>(ei, cnt, bucket, tid);
  }
  grid.sync();  // x16 + bucket + cnt visible grid-wide

  // phase 2: gather. One wave per node, grid-stride (~25 nodes/wave).
  int wave = tid >> 6;
  int j = tid & 63;
#pragma unroll 1
  for (int i = blockIdx.x * 4 + wave; i < NN; i += GRID * 4) {
    int deg = cnt[i];
    float acc = gather_node(i, deg, x16, bucket, j);
    float inv = 1.0f / fmaxf((float)deg, 1.0f);
    float self = bf2f(x16[i * DD + j]);
    out[i * DD + j] = fmaxf(fmaf(acc, inv, self + bias[j]), 0.0f);
  }
}

// ===========================================================================
// Fallback pipeline (verified round-2 kernels) — used if coop launch fails.
// ===========================================================================
__global__ __launch_bounds__(256) void linear_mfma_kernel(
    const float* __restrict__ nf, const float* __restrict__ W,
    const float* __restrict__ b_lin, u16* __restrict__ x16,
    int* __restrict__ cnt) {
  __shared__ u16 Wsh[64 * 72];
  int tid = threadIdx.x;
  if (blockIdx.x < NB) {
    int zi = blockIdx.x * 256 + tid;
    if (zi < NN) cnt[zi] = 0;
  }
#pragma unroll
  for (int s = 0; s < 16; ++s) {
    int idx = s * 256 + tid;
    Wsh[(idx >> 6) * 72 + (idx & 63)] = f2bf(W[idx]);
  }
  __syncthreads();
  // one tile per wave, no stride loop needed (grid covers NTILE exactly)
  int wave = tid >> 6;
  int tile = blockIdx.x * 4 + wave;
  if (tile >= NTILE) return;
  // reuse templated body with STRIDE large enough for a single iteration
  {
    int lane = tid & 63;
    int m = lane & 15;
    int quad = lane >> 4;
    int rowbase = tile * 16;
    bf16x8 bfrag[4][2];
#pragma unroll
    for (int c = 0; c < 4; ++c)
#pragma unroll
      for (int ks = 0; ks < 2; ++ks)
        bfrag[c][ks] = *(const bf16x8*)&Wsh[(c * 16 + m) * 72 + ks * 32 + quad * 8];
    bf16x8 afrag[2];
#pragma unroll
    for (int ks = 0; ks < 2; ++ks) {
      const float* p = nf + (rowbase + m) * DD + ks * 32 + quad * 8;
      float4 lo = *(const float4*)p;
      float4 hi = *(const float4*)(p + 4);
      bf16x8 a;
      a[0] = (short)f2bf(lo.x); a[1] = (short)f2bf(lo.y);
      a[2] = (short)f2bf(lo.z); a[3] = (short)f2bf(lo.w);
      a[4] = (short)f2bf(hi.x); a[5] = (short)f2bf(hi.y);
      a[6] = (short)f2bf(hi.z); a[7] = (short)f2bf(hi.w);
      afrag[ks] = a;
    }
    f32x4 acc[4];
#pragma unroll
    for (int c = 0; c < 4; ++c) {
      acc[c][0] = 0.0f; acc[c][1] = 0.0f; acc[c][2] = 0.0f; acc[c][3] = 0.0f;
    }
#pragma unroll
    for (int c = 0; c < 4; ++c) {
      acc[c] = __builtin_amdgcn_mfma_f32_16x16x32_bf16(afrag[0], bfrag[c][0], acc[c], 0, 0, 0);
      acc[c] = __builtin_amdgcn_mfma_f32_16x16x32_bf16(afrag[1], bfrag[c][1], acc[c], 0, 0, 0);
    }
#pragma unroll
    for (int c = 0; c < 4; ++c) {
      int gcol = c * 16 + m;
      float bl = b_lin[gcol];
#pragma unroll
      for (int r = 0; r < 4; ++r)
        x16[(rowbase + quad * 4 + r) * DD + gcol] = f2bf(acc[c][r] + bl);
    }
  }
}

__global__ __launch_bounds__(256) void scatter_kernel(
    const int* __restrict__ ei, int* __restrict__ cnt,
    u16* __restrict__ bucket) {
  do_scatter<NVB>(ei, cnt, bucket, (int)threadIdx.x);  // 1 vb per block
}

__global__ __launch_bounds__(256) void gather_kernel(
    const u16* __restrict__ x16, const u16* __restrict__ bucket,
    const int* __restrict__ cnt, const float* __restrict__ bias,
    float* __restrict__ out) {
  int i = blockIdx.x * 4 + (threadIdx.x >> 6);  // grid exact: NN/4 blocks
  int j = threadIdx.x & 63;
  int deg = cnt[i];
  float acc = gather_node(i, deg, x16, bucket, j);
  float inv = 1.0f / fmaxf((float)deg, 1.0f);
  float self = bf2f(x16[i * DD + j]);
  out[i * DD + j] = fmaxf(fmaf(acc, inv, self + bias[j]), 0.0f);
}

extern "C" void kernel_launch(void* const* d_in, const int* in_sizes, int n_in,
                              void* d_out, int out_size, void* d_ws, size_t ws_size,
                              hipStream_t stream) {
  const float* nf    = (const float*)d_in[0];
  const int*   ei    = (const int*)d_in[1];
  const float* W     = (const float*)d_in[2];
  const float* b_lin = (const float*)d_in[3];
  const float* bias  = (const float*)d_in[4];
  float* out = (float*)d_out;

  // workspace layout (x16 MUST be at base: gather's garbage-index reads land
  // in [0, 8.4 MB) = x16 + bucket region, all inside d_ws)
  u16* x16    = (u16*)d_ws;                        // N*D bf16      (6.4 MB)
  u16* bucket = x16 + (size_t)NN * DD;             // N*BCAP u16    (6.4 MB)
  int* cnt    = (int*)(bucket + (size_t)NN * BCAP);// N ints        (200 KB)

  void* args[] = {(void*)&nf, (void*)&ei, (void*)&W, (void*)&b_lin,
                  (void*)&bias, (void*)&x16, (void*)&bucket, (void*)&cnt,
                  (void*)&out};
  hipError_t err = hipLaunchCooperativeKernel(
      (const void*)mega_kernel, dim3(GRID), dim3(256), args, 0, stream);
  if (err != hipSuccess) {
    // fallback: verified 3-kernel pipeline (round-2, 135.9 us)
    linear_mfma_kernel<<<(NTILE + 3) / 4, 256, 0, stream>>>(nf, W, b_lin, x16, cnt);
    scatter_kernel<<<NVB, 256, 0, stream>>>(ei, cnt, bucket);
    gather_kernel<<<NN / 4, 256, 0, stream>>>(x16, bucket, cnt, bias, out);
  }
}

// Round 5
// 130.743 us; speedup vs baseline: 2.1113x; 2.1113x over previous
//
#include <hip/hip_runtime.h>
#include <hip/hip_bf16.h>

#define NN 50000
#define DD 64
#define EE 800000
#define NTILE 3125  // NN/16 row tiles (exact)
#define NSLICE 128  // edge slices for scatter
#define ESL 6250    // EE/NSLICE edges per slice
#define DRNG 6250   // NN/8 dst nodes per XCD range
#define BCAP 64     // bucket capacity per node (P(deg>64) ~ 1e-14 for Poisson(16))
#define NVB 1024    // scatter blocks (NSLICE*8), first in fused grid
#define NLB 782     // linear blocks: ceil(NTILE/4)

typedef unsigned short u16;
typedef unsigned int u32;
typedef __attribute__((ext_vector_type(8))) short bf16x8;
typedef __attribute__((ext_vector_type(4))) float f32x4;

__device__ __forceinline__ float bf2f(u16 u) {
  u32 t = ((u32)u) << 16;
  return __builtin_bit_cast(float, t);
}
__device__ __forceinline__ u16 f2bf(float f) {
  u32 b = __builtin_bit_cast(u32, f);
  u32 r = (b + 0x7FFF + ((b >> 16) & 1)) >> 16;
  return (u16)r;
}

// ---------------------------------------------------------------------------
// fused linear+scatter: one dispatch, two data-independent roles.
//   blocks [0, NVB):      scatter (atomic-latency work; dispatched first so
//                         it overlaps the linear blocks' MFMA/HBM work)
//   blocks [NVB, NVB+NLB): linear x = nf @ W.T + b_lin -> bf16 x16[N][64]
// cnt[] must be zeroed by the preceding hipMemsetAsync (stream-ordered).
//
// scatter: pos = atomicAdd claims a bucket slot; cnt doubles as claim counter
// and final degree. XCD-sliced: block b handles dst range r=b&7 over edge
// slice sl=b>>3; with round-robin block->XCD mapping, r == XCD id, so each
// node's bucket lines + cnt counter stay in one XCD's L2 (perf heuristic;
// correctness independent of mapping). pos>=BCAP claims dropped (keeps all
// writes in-bounds unconditionally; never triggers for this input).
//
// linear: C/D mapping col=lane&15, row=(lane>>4)*4+reg [verified m89/m91].
// Interleaved [N][64] bf16 rows = 128 B/row = full cache line per random
// gather access (round-1 planar split measured WORSE; keep interleaved).
// ---------------------------------------------------------------------------
__global__ __launch_bounds__(256) void fused_ls_kernel(
    const float* __restrict__ nf, const int* __restrict__ ei,
    const float* __restrict__ W, const float* __restrict__ b_lin,
    u16* __restrict__ x16, u16* __restrict__ bucket, int* __restrict__ cnt) {
  __shared__ u16 Wsh[64 * 72];
  int b = blockIdx.x;
  int tid = threadIdx.x;

  if (b < NVB) {
    // ---- scatter role ----
    int r = b & 7;
    int sl = b >> 3;
    int rlo = r * DRNG;
    int ebase = sl * ESL;
    int eend = ebase + ESL;
#pragma unroll 1
    for (int it = 0; it < 13; ++it) {
      int e = ebase + it * 512 + tid * 2;
      if (e < eend) {
        int4 p = *(const int4*)(ei + 2 * e);  // (src0,dst0,src1,dst1)
        if ((u32)(p.y - rlo) < (u32)DRNG) {
          int pos = atomicAdd(&cnt[p.y], 1);
          if (pos < BCAP) bucket[p.y * BCAP + pos] = (u16)p.x;
        }
        if ((u32)(p.w - rlo) < (u32)DRNG) {
          int pos = atomicAdd(&cnt[p.w], 1);
          if (pos < BCAP) bucket[p.w * BCAP + pos] = (u16)p.z;
        }
      }
    }
    return;
  }

  // ---- linear role ----
#pragma unroll
  for (int s = 0; s < 16; ++s) {
    int idx = s * 256 + tid;
    Wsh[(idx >> 6) * 72 + (idx & 63)] = f2bf(W[idx]);
  }
  __syncthreads();  // block-uniform path: safe

  int wave = tid >> 6;
  int lane = tid & 63;
  int tile = (b - NVB) * 4 + wave;
  if (tile >= NTILE) return;  // after the only barrier: safe

  int m = lane & 15;
  int quad = lane >> 4;
  int rowbase = tile * 16;

  bf16x8 bfrag[4][2];
#pragma unroll
  for (int c = 0; c < 4; ++c) {
#pragma unroll
    for (int ks = 0; ks < 2; ++ks) {
      const u16* p = &Wsh[(c * 16 + m) * 72 + ks * 32 + quad * 8];
      bfrag[c][ks] = *(const bf16x8*)p;
    }
  }

  bf16x8 afrag[2];
#pragma unroll
  for (int ks = 0; ks < 2; ++ks) {
    const float* p = nf + (rowbase + m) * DD + ks * 32 + quad * 8;
    float4 lo = *(const float4*)p;
    float4 hi = *(const float4*)(p + 4);
    bf16x8 a;
    a[0] = (short)f2bf(lo.x); a[1] = (short)f2bf(lo.y);
    a[2] = (short)f2bf(lo.z); a[3] = (short)f2bf(lo.w);
    a[4] = (short)f2bf(hi.x); a[5] = (short)f2bf(hi.y);
    a[6] = (short)f2bf(hi.z); a[7] = (short)f2bf(hi.w);
    afrag[ks] = a;
  }

  f32x4 acc[4];
#pragma unroll
  for (int c = 0; c < 4; ++c) {
    acc[c][0] = 0.0f; acc[c][1] = 0.0f; acc[c][2] = 0.0f; acc[c][3] = 0.0f;
  }
#pragma unroll
  for (int c = 0; c < 4; ++c) {
    acc[c] = __builtin_amdgcn_mfma_f32_16x16x32_bf16(afrag[0], bfrag[c][0], acc[c], 0, 0, 0);
    acc[c] = __builtin_amdgcn_mfma_f32_16x16x32_bf16(afrag[1], bfrag[c][1], acc[c], 0, 0, 0);
  }

#pragma unroll
  for (int c = 0; c < 4; ++c) {
    int gcol = c * 16 + m;
    float bl = b_lin[gcol];
#pragma unroll
    for (int r2 = 0; r2 < 4; ++r2) {
      int grow = rowbase + quad * 4 + r2;
      x16[grow * DD + gcol] = f2bf(acc[c][r2] + bl);
    }
  }
}

// ---------------------------------------------------------------------------
// gather (unchanged from verified round-2): one wave per node. One coalesced
// 128 B load grabs the node's 64 bucket entries; readlane broadcasts each to
// SGPR so row loads issue off scalar bases with high MLP. Lanes >= deg hold
// garbage u16 indices; reads stay inside d_ws (8.4 MB) and contributions are
// cndmask-gated to 0 (NaN-safe: select, not multiply).
// ---------------------------------------------------------------------------
template <int BASE, int LEN>
__device__ __forceinline__ float chunkN(int my, int n,
                                        const u16* __restrict__ x16, int j) {
  float v[LEN];
#pragma unroll
  for (int k = 0; k < LEN; ++k) {
    int s = __builtin_amdgcn_readlane(my, BASE + k);
    v[k] = bf2f(x16[s * DD + j]);
  }
  float a = 0.0f;
#pragma unroll
  for (int k = 0; k < LEN; ++k) a += (BASE + k < n) ? v[k] : 0.0f;
  return a;
}

__global__ __launch_bounds__(256) void gather_kernel(
    const u16* __restrict__ x16, const u16* __restrict__ bucket,
    const int* __restrict__ cnt, const float* __restrict__ bias,
    float* __restrict__ out) {
  int i = blockIdx.x * 4 + (threadIdx.x >> 6);  // grid exact: NN/4 blocks
  int j = threadIdx.x & 63;
  int deg = cnt[i];
  int win = deg < BCAP ? deg : BCAP;
  int my = (int)bucket[i * BCAP + j];

  float acc = chunkN<0, 16>(my, win, x16, j);
  if (win > 16) acc += chunkN<16, 8>(my, win, x16, j);
  if (win > 24) acc += chunkN<24, 8>(my, win, x16, j);
  if (win > 32) acc += chunkN<32, 8>(my, win, x16, j);
  if (win > 40) acc += chunkN<40, 8>(my, win, x16, j);
  if (win > 48) acc += chunkN<48, 8>(my, win, x16, j);
  if (win > 56) acc += chunkN<56, 8>(my, win, x16, j);

  float inv = 1.0f / fmaxf((float)deg, 1.0f);
  float self = bf2f(x16[i * DD + j]);
  out[i * DD + j] = fmaxf(fmaf(acc, inv, self + bias[j]), 0.0f);
}

extern "C" void kernel_launch(void* const* d_in, const int* in_sizes, int n_in,
                              void* d_out, int out_size, void* d_ws, size_t ws_size,
                              hipStream_t stream) {
  const float* nf    = (const float*)d_in[0];
  const int*   ei    = (const int*)d_in[1];
  const float* W     = (const float*)d_in[2];
  const float* b_lin = (const float*)d_in[3];
  const float* bias  = (const float*)d_in[4];
  float* out = (float*)d_out;

  // workspace layout (x16 MUST be at base: gather's garbage-index reads land
  // in [0, 8.4 MB) = x16 + bucket region, all inside d_ws)
  u16* x16    = (u16*)d_ws;                        // N*D bf16      (6.4 MB)
  u16* bucket = x16 + (size_t)NN * DD;             // N*BCAP u16    (6.4 MB)
  int* cnt    = (int*)(bucket + (size_t)NN * BCAP);// N ints        (200 KB)
  // total ~13 MB << ws_size

  // zero claim counters (stream-ordered; capture-safe async blit, ~200 KB)
  hipMemsetAsync(cnt, 0, NN * sizeof(int), stream);
  fused_ls_kernel<<<NVB + NLB, 256, 0, stream>>>(nf, ei, W, b_lin, x16, bucket, cnt);
  gather_kernel<<<NN / 4, 256, 0, stream>>>(x16, bucket, cnt, bias, out);
}